// Round 1
// 693.878 us; speedup vs baseline: 1.0032x; 1.0032x over previous
//
#include <hip/hip_runtime.h>
#include <stdint.h>

#define TOKENS 8192
#define IN_F   3072
#define OUT_F  8192
#define GROUP  128

// GEMM: 256x256 tile, BK=64, 8 waves (2M x 4N), 512 threads.
// m201-style 8-phase schedule: per K-tile 4 phases, each
//   {ds_read reg subtile | stage 1 half-tile to other buf | barrier |
//    setprio(1) + 16 MFMA + setprio(0) | barrier}
// counted s_waitcnt vmcnt(2) once per K-tile (never drains to 0 in steady
// state -> loads stay in flight across barriers). LDS 128 KiB 2x double
// buffered, 16B-chunk XOR swizzle: slot s of row r holds global chunk
// s ^ (r&7)  ->  fragment ds_read_b128 is 2-way bank aliased = free.
#define BM 256
#define BN 256
#define BK 64
#define NT (IN_F / BK)   // 48 K-tiles

typedef __bf16 bf16x8 __attribute__((ext_vector_type(8)));
typedef float  f32x4  __attribute__((ext_vector_type(4)));

// RNE float -> bf16 bits
__device__ __forceinline__ uint32_t f2bf(float f) {
    union { float f; uint32_t u; } v; v.f = f;
    uint32_t u = v.u;
    return (u + 0x7fffu + ((u >> 16) & 1u)) >> 16;
}

// async global -> LDS, 16 bytes per lane (global_load_lds_dwordx4)
__device__ __forceinline__ void async_cp16(const uint16_t* g, uint16_t* l) {
    __builtin_amdgcn_global_load_lds(
        (const __attribute__((address_space(1))) void*)g,
        (__attribute__((address_space(3))) void*)l,
        16, 0, 0);
}

// raw workgroup barrier WITHOUT vmcnt drain (do NOT use __syncthreads here)
__device__ __forceinline__ void wg_barrier() {
    asm volatile("" ::: "memory");
    __builtin_amdgcn_s_barrier();
    asm volatile("" ::: "memory");
}

// ---------------------------------------------------------------------------
// Prep (one launch): blocks [0,12288) dequant packed int4 -> bf16 W;
// blocks [12288,24576) convert x fp32 -> bf16.
// ---------------------------------------------------------------------------
__global__ __launch_bounds__(256) void prep(const int* __restrict__ packed,
                                            const float* __restrict__ scales,
                                            const float* __restrict__ x,
                                            uint16_t* __restrict__ W,
                                            uint16_t* __restrict__ xb) {
    if (blockIdx.x < 12288) {
        const int t   = blockIdx.x * 256 + threadIdx.x;
        const int idx = t * 4;                 // packed-element index
        const int row  = idx / (IN_F / 2);     // 1536 packed per row
        const int pcol = idx - row * (IN_F / 2);
        const int grp  = pcol >> 6;            // 64 packed = 128 cols per group
        const float s  = scales[row * (IN_F / GROUP) + grp];

        const int4 p = *(const int4*)(packed + idx);
        int vals[4] = {p.x, p.y, p.z, p.w};
        uint32_t w[4];
#pragma unroll
        for (int i = 0; i < 4; ++i) {
            int b  = vals[i] & 255;
            int lo = b & 15;        lo = (lo >= 8) ? lo - 16 : lo;
            int hi = (b >> 4) & 15; hi = (hi >= 8) ? hi - 16 : hi;
            uint32_t e = f2bf((float)lo * s);   // even column
            uint32_t o = f2bf((float)hi * s);   // odd column
            w[i] = e | (o << 16);
        }
        uint4 res = {w[0], w[1], w[2], w[3]};
        *(uint4*)(W + (size_t)idx * 2) = res;
    } else {
        const size_t idx = ((size_t)(blockIdx.x - 12288) * 256 + threadIdx.x) * 8;
        const float4 a = *(const float4*)(x + idx);
        const float4 b = *(const float4*)(x + idx + 4);
        uint32_t w0 = f2bf(a.x) | (f2bf(a.y) << 16);
        uint32_t w1 = f2bf(a.z) | (f2bf(a.w) << 16);
        uint32_t w2 = f2bf(b.x) | (f2bf(b.y) << 16);
        uint32_t w3 = f2bf(b.z) | (f2bf(b.w) << 16);
        uint4 res = {w0, w1, w2, w3};
        *(uint4*)(xb + idx) = res;
    }
}

// ---------------------------------------------------------------------------
// GEMM: C[M,N] = A[M,K] * B[N,K]^T + bias  (bf16 in, fp32 out)
// ---------------------------------------------------------------------------
__global__ __launch_bounds__(512, 2) void gemm_bt(const uint16_t* __restrict__ A,
                                                  const uint16_t* __restrict__ B,
                                                  const float* __restrict__ bias,
                                                  float* __restrict__ C) {
    constexpr int K = IN_F;
    constexpr int N = OUT_F;

    // [buf][0=A,1=B][row*64 + col], 2*2*16384*2B = 128 KiB
    __shared__ __align__(16) uint16_t lds[2][2][BM * BK];

    const int t    = threadIdx.x;
    const int lane = t & 63;
    const int wave = t >> 6;

    // XCD-aware bijective swizzle: 1024 wgs % 8 == 0 -> each XCD gets 128
    // consecutive tiles = 4 full M-panels (A reuse in its L2).
    const int wg  = blockIdx.x;
    const int swz = (wg & 7) * 128 + (wg >> 3);
    const int bx  = swz & 31;          // N tile index (fast within XCD chunk)
    const int by  = swz >> 5;          // M tile index

    const int wm = (wave >> 2) * 128;  // wave M offset: 0 / 128
    const int wn = (wave & 3) * 64;    // wave N offset: 0 / 64 / 128 / 192

    const int fr = lane & 15;          // row within 16-tile
    const int qq = lane >> 4;          // k-chunk sub-index 0..3
    const int fx = fr & 7;             // read-side swizzle XOR (== row&7)

    // staging: thread covers rows (t>>3) + {0,64} of a 128-row half, slot t&7
    const int r0 = t >> 3;                 // 0..63
    const int sx = (t & 7) ^ (r0 & 7);     // swizzled global chunk (inv. +64)

    f32x4 acc[8][4] = {};

    // half-tile stream s = 4*tile + slot; slot: 0=A.h0 1=A.h1 2=B.h0 3=B.h1
    // issue schedule: stream s issued at global phase s-5; consumed at the
    // first phase of its tile. 2 global_load_lds per stream per thread.
    auto stage = [&](int s) {
        const int Tt   = s >> 2;
        const int slot = s & 3;
        const int half = slot & 1;
        const uint16_t* gb = (slot & 2) ? B : A;
        const int rowBase  = ((slot & 2) ? bx : by) * 256 + half * 128;
        uint16_t* ld = &lds[Tt & 1][slot >> 1][half * 8192];
        const int kc = Tt * BK + sx * 8;
#pragma unroll
        for (int p = 0; p < 2; ++p) {
            const int r = r0 + 64 * p;
            async_cp16(gb + (size_t)(rowBase + r) * K + kc, ld + 4096 * p + t * 8);
        }
    };

    // prologue: tile0 all 4 halves + A.h0 of tile1 (streams 0..4);
    // vmcnt(2) allows stream 4 (2 loads) outstanding, forces tile0 resident.
#pragma unroll
    for (int s = 0; s < 5; ++s) stage(s);
    asm volatile("s_waitcnt vmcnt(2)" ::: "memory");
    __builtin_amdgcn_sched_barrier(0);
    wg_barrier();

    for (int T = 0; T < NT; ++T) {
        const uint16_t* sA = lds[T & 1][0];
        const uint16_t* sB = lds[T & 1][1];
        const int s0 = 4 * T;
        bf16x8 af[4][2], bf[4][2];

        // ---- P0: read A-lo (8) + B j0-1 (4); stage A.h1 of T+1 ----
#pragma unroll
        for (int i = 0; i < 4; ++i)
#pragma unroll
            for (int ks = 0; ks < 2; ++ks)
                af[i][ks] = *(const bf16x8*)(sA + (wm + i * 16 + fr) * 64 +
                                             (((ks * 4 + qq) ^ fx) * 8));
#pragma unroll
        for (int j = 0; j < 2; ++j)
#pragma unroll
            for (int ks = 0; ks < 2; ++ks)
                bf[j][ks] = *(const bf16x8*)(sB + (wn + j * 16 + fr) * 64 +
                                             (((ks * 4 + qq) ^ fx) * 8));
        if (T < NT - 1) stage(s0 + 5);
        wg_barrier();
        __builtin_amdgcn_s_setprio(1);
#pragma unroll
        for (int i = 0; i < 4; ++i)
#pragma unroll
            for (int j = 0; j < 2; ++j)
#pragma unroll
                for (int ks = 0; ks < 2; ++ks)
                    acc[i][j] = __builtin_amdgcn_mfma_f32_16x16x32_bf16(
                        af[i][ks], bf[j][ks], acc[i][j], 0, 0, 0);
        __builtin_amdgcn_s_setprio(0);
        wg_barrier();

        // ---- P1: read B j2-3 (4); stage B.h0 of T+1 ----
#pragma unroll
        for (int j = 2; j < 4; ++j)
#pragma unroll
            for (int ks = 0; ks < 2; ++ks)
                bf[j][ks] = *(const bf16x8*)(sB + (wn + j * 16 + fr) * 64 +
                                             (((ks * 4 + qq) ^ fx) * 8));
        if (T < NT - 1) stage(s0 + 6);
        wg_barrier();
        __builtin_amdgcn_s_setprio(1);
#pragma unroll
        for (int i = 0; i < 4; ++i)
#pragma unroll
            for (int j = 2; j < 4; ++j)
#pragma unroll
                for (int ks = 0; ks < 2; ++ks)
                    acc[i][j] = __builtin_amdgcn_mfma_f32_16x16x32_bf16(
                        af[i][ks], bf[j][ks], acc[i][j], 0, 0, 0);
        __builtin_amdgcn_s_setprio(0);
        wg_barrier();

        // ---- P2: read A-hi (8, overwrite af); stage B.h1 of T+1 ----
#pragma unroll
        for (int i = 0; i < 4; ++i)
#pragma unroll
            for (int ks = 0; ks < 2; ++ks)
                af[i][ks] = *(const bf16x8*)(sA + (wm + (i + 4) * 16 + fr) * 64 +
                                             (((ks * 4 + qq) ^ fx) * 8));
        if (T < NT - 1) stage(s0 + 7);
        wg_barrier();
        __builtin_amdgcn_s_setprio(1);
#pragma unroll
        for (int i = 0; i < 4; ++i)
#pragma unroll
            for (int j = 0; j < 2; ++j)
#pragma unroll
                for (int ks = 0; ks < 2; ++ks)
                    acc[i + 4][j] = __builtin_amdgcn_mfma_f32_16x16x32_bf16(
                        af[i][ks], bf[j][ks], acc[i + 4][j], 0, 0, 0);
        __builtin_amdgcn_s_setprio(0);
        wg_barrier();

        // ---- P3: no ds_read; stage A.h0 of T+2 (buf slot free after P2) ----
        if (T < NT - 2) stage(s0 + 8);
        wg_barrier();
        __builtin_amdgcn_s_setprio(1);
#pragma unroll
        for (int i = 0; i < 4; ++i)
#pragma unroll
            for (int j = 2; j < 4; ++j)
#pragma unroll
                for (int ks = 0; ks < 2; ++ks)
                    acc[i + 4][j] = __builtin_amdgcn_mfma_f32_16x16x32_bf16(
                        af[i][ks], bf[j][ks], acc[i + 4][j], 0, 0, 0);
        __builtin_amdgcn_s_setprio(0);
        // tile-boundary wait: force all of tile T+1's halves resident while
        // keeping the newest stream (A.h0 of T+2, 2 loads) in flight.
        if (T < NT - 2) {
            asm volatile("s_waitcnt vmcnt(2)" ::: "memory");
        } else {
            asm volatile("s_waitcnt vmcnt(0)" ::: "memory");
        }
        __builtin_amdgcn_sched_barrier(0);
        wg_barrier();
    }

    // --- epilogue: C/D layout col=lane&15, row=(lane>>4)*4+reg ---
    const int cr = (lane >> 4) * 4;
    const int cc = lane & 15;
#pragma unroll
    for (int j = 0; j < 4; ++j) {
        const int col = bx * BN + wn + j * 16 + cc;
        const float bv = bias[col];
#pragma unroll
        for (int i = 0; i < 8; ++i) {
            const size_t base = (size_t)(by * BM + wm + i * 16 + cr) * N + col;
#pragma unroll
            for (int r = 0; r < 4; ++r)
                C[base + (size_t)r * N] = acc[i][j][r] + bv;
        }
    }
}

extern "C" void kernel_launch(void* const* d_in, const int* in_sizes, int n_in,
                              void* d_out, int out_size, void* d_ws, size_t ws_size,
                              hipStream_t stream) {
    const float* x      = (const float*)d_in[0];   // [8192, 3072] fp32
    const int*   packed = (const int*)d_in[1];     // [8192, 1536] int32 (byte vals)
    const float* scales = (const float*)d_in[2];   // [8192, 24] fp32
    const float* bias   = (const float*)d_in[3];   // [8192] fp32
    float*       out    = (float*)d_out;           // [8192, 8192] fp32

    uint16_t* W  = (uint16_t*)d_ws;                                     // 50.3 MB bf16
    uint16_t* Xb = (uint16_t*)((char*)d_ws + (size_t)OUT_F * IN_F * 2); // 50.3 MB bf16

    prep<<<24576, 256, 0, stream>>>(packed, scales, x, W, Xb);

    gemm_bt<<<dim3(1024), 512, 0, stream>>>(Xb, W, bias, out);
}